// Round 1
// baseline (10413.680 us; speedup 1.0000x reference)
//
#include <hip/hip_runtime.h>
#include <hip/hip_bf16.h>

// Seq2seq GRU (2-layer enc T=192, 2-layer dec T=96), B=128, H=1024.
// Strategy: decouple layers (L0 fully, then L1), bf16 MFMA for all matmuls,
// fp32 master hidden state, fp32 output projection.
// Chain: 576 small step kernels, each computing one GRU cell update fused
// (gh matmul K=1024 [+ gi matmul], gates, state update).

#define H 1024
#define G 3072   /* 3*H */
#define BB 128
#define TENC 192
#define TDEC 96

typedef __attribute__((ext_vector_type(4))) float f32x4;
typedef __attribute__((ext_vector_type(8))) short bf16x8;

__device__ __forceinline__ float sigmoidf_(float x) {
    return 1.0f / (1.0f + __expf(-x));
}

__device__ __forceinline__ short f2bf_rne(float f) {
    union { float f; unsigned u; } v; v.f = f;
    unsigned r = v.u + 0x7fffu + ((v.u >> 16) & 1u);
    return (short)(r >> 16);
}

__global__ __launch_bounds__(256) void k_f2bf(const float* __restrict__ in,
                                              short* __restrict__ out, int n) {
    for (int i = blockIdx.x * 256 + threadIdx.x; i < n; i += gridDim.x * 256)
        out[i] = f2bf_rne(in[i]);
}

// dec_in[b][t][c]: t==0 -> x_enc[b][191][c], else x_dec[b][t-1][c]
__global__ __launch_bounds__(256) void k_build_decin(const float* __restrict__ x_enc,
                                                     const float* __restrict__ x_dec,
                                                     short* __restrict__ out) {
    int i = blockIdx.x * 256 + threadIdx.x;
    if (i >= BB * TDEC * 32) return;
    int c = i & 31;
    int t = (i >> 5) % TDEC;
    int b = i / (TDEC * 32);
    float v = (t == 0) ? x_enc[(size_t)b * TENC * 32 + 191 * 32 + c]
                       : x_dec[(size_t)b * TDEC * 32 + (t - 1) * 32 + c];
    out[i] = f2bf_rne(v);
}

// GRU step, input dim 32 (layer 0). One wave = 16x16 tile of h', all 3 gates.
// grid (8, 64), block 64.
__global__ __launch_bounds__(64) void k_step_small(
    const short* __restrict__ xbf, int xstride, int xoff,
    const short* __restrict__ wih,   // [G][32]  bf16
    const short* __restrict__ whh,   // [G][H]   bf16
    const float* __restrict__ bih, const float* __restrict__ bhh,
    const short* __restrict__ hbf_old, const float* __restrict__ hf_old,
    short* __restrict__ hbf_new, float* __restrict__ hf_new)
{
    const int lane = threadIdx.x & 63;
    const int lr = lane & 15;
    const int kg = lane >> 4;
    const int b0 = blockIdx.x * 16;
    const int i0 = blockIdx.y * 16;

    f32x4 accR = {0.f, 0.f, 0.f, 0.f};
    f32x4 accZ = accR, accGN = accR, accHN = accR;

    const short* ar = hbf_old + (size_t)(b0 + lr) * H + kg * 8;
    const short* wr = whh + (size_t)(i0 + lr) * H + kg * 8;
    const short* wz = wr + (size_t)H * H;
    const short* wn = wr + (size_t)(2 * H) * H;

    #pragma unroll 4
    for (int kk = 0; kk < H; kk += 32) {
        bf16x8 a  = *(const bf16x8*)(ar + kk);
        bf16x8 br = *(const bf16x8*)(wr + kk);
        bf16x8 bz = *(const bf16x8*)(wz + kk);
        bf16x8 bn = *(const bf16x8*)(wn + kk);
        accR  = __builtin_amdgcn_mfma_f32_16x16x32_bf16(a, br, accR, 0, 0, 0);
        accZ  = __builtin_amdgcn_mfma_f32_16x16x32_bf16(a, bz, accZ, 0, 0, 0);
        accHN = __builtin_amdgcn_mfma_f32_16x16x32_bf16(a, bn, accHN, 0, 0, 0);
    }
    {   // gi: K=32 input matmul, single MFMA chunk per gate
        bf16x8 a  = *(const bf16x8*)(xbf + (size_t)(b0 + lr) * xstride + xoff + kg * 8);
        bf16x8 br = *(const bf16x8*)(wih + (size_t)(i0 + lr) * 32 + kg * 8);
        bf16x8 bz = *(const bf16x8*)(wih + (size_t)(H + i0 + lr) * 32 + kg * 8);
        bf16x8 bn = *(const bf16x8*)(wih + (size_t)(2 * H + i0 + lr) * 32 + kg * 8);
        accR  = __builtin_amdgcn_mfma_f32_16x16x32_bf16(a, br, accR, 0, 0, 0);
        accZ  = __builtin_amdgcn_mfma_f32_16x16x32_bf16(a, bz, accZ, 0, 0, 0);
        accGN = __builtin_amdgcn_mfma_f32_16x16x32_bf16(a, bn, accGN, 0, 0, 0);
    }
    const int col = i0 + lr;
    const float bR  = bih[col] + bhh[col];
    const float bZ  = bih[H + col] + bhh[H + col];
    const float bGN = bih[2 * H + col];
    const float bHN = bhh[2 * H + col];
    #pragma unroll
    for (int r = 0; r < 4; ++r) {
        int row = b0 + kg * 4 + r;            // C/D: row = 4*(lane>>4)+reg
        float vr = sigmoidf_(accR[r] + bR);
        float vz = sigmoidf_(accZ[r] + bZ);
        float vn = tanhf(accGN[r] + bGN + vr * (accHN[r] + bHN));
        float ho = hf_old[(size_t)row * H + col];
        float hn = (1.0f - vz) * vn + vz * ho;
        hf_new[(size_t)row * H + col] = hn;
        hbf_new[(size_t)row * H + col] = f2bf_rne(hn);
    }
}

// GRU step, input dim H (layer 1): fused gi (K=1024) + gh (K=1024).
// grid (8, 64), block 64.
__global__ __launch_bounds__(64) void k_step_big(
    const short* __restrict__ ybf,   // [BB][H] layer-0 output at t (gi input)
    const short* __restrict__ wih,   // [G][H]
    const short* __restrict__ whh,   // [G][H]
    const float* __restrict__ bih, const float* __restrict__ bhh,
    const short* __restrict__ hbf_old, const float* __restrict__ hf_old,
    short* __restrict__ hbf_new, float* __restrict__ hf_new)
{
    const int lane = threadIdx.x & 63;
    const int lr = lane & 15;
    const int kg = lane >> 4;
    const int b0 = blockIdx.x * 16;
    const int i0 = blockIdx.y * 16;

    f32x4 accR = {0.f, 0.f, 0.f, 0.f};
    f32x4 accZ = accR, accGN = accR, accHN = accR;

    const short* ay = ybf + (size_t)(b0 + lr) * H + kg * 8;
    const short* ah = hbf_old + (size_t)(b0 + lr) * H + kg * 8;
    const short* wir = wih + (size_t)(i0 + lr) * H + kg * 8;
    const short* wiz = wir + (size_t)H * H;
    const short* win = wir + (size_t)(2 * H) * H;
    const short* whr = whh + (size_t)(i0 + lr) * H + kg * 8;
    const short* whz = whr + (size_t)H * H;
    const short* whn = whr + (size_t)(2 * H) * H;

    #pragma unroll 2
    for (int kk = 0; kk < H; kk += 32) {
        bf16x8 vy  = *(const bf16x8*)(ay + kk);
        bf16x8 vh  = *(const bf16x8*)(ah + kk);
        bf16x8 vir = *(const bf16x8*)(wir + kk);
        bf16x8 viz = *(const bf16x8*)(wiz + kk);
        bf16x8 vin = *(const bf16x8*)(win + kk);
        bf16x8 vhr = *(const bf16x8*)(whr + kk);
        bf16x8 vhz = *(const bf16x8*)(whz + kk);
        bf16x8 vhn = *(const bf16x8*)(whn + kk);
        accR  = __builtin_amdgcn_mfma_f32_16x16x32_bf16(vy, vir, accR, 0, 0, 0);
        accR  = __builtin_amdgcn_mfma_f32_16x16x32_bf16(vh, vhr, accR, 0, 0, 0);
        accZ  = __builtin_amdgcn_mfma_f32_16x16x32_bf16(vy, viz, accZ, 0, 0, 0);
        accZ  = __builtin_amdgcn_mfma_f32_16x16x32_bf16(vh, vhz, accZ, 0, 0, 0);
        accGN = __builtin_amdgcn_mfma_f32_16x16x32_bf16(vy, vin, accGN, 0, 0, 0);
        accHN = __builtin_amdgcn_mfma_f32_16x16x32_bf16(vh, vhn, accHN, 0, 0, 0);
    }
    const int col = i0 + lr;
    const float bR  = bih[col] + bhh[col];
    const float bZ  = bih[H + col] + bhh[H + col];
    const float bGN = bih[2 * H + col];
    const float bHN = bhh[2 * H + col];
    #pragma unroll
    for (int r = 0; r < 4; ++r) {
        int row = b0 + kg * 4 + r;
        float vr = sigmoidf_(accR[r] + bR);
        float vz = sigmoidf_(accZ[r] + bZ);
        float vn = tanhf(accGN[r] + bGN + vr * (accHN[r] + bHN));
        float ho = hf_old[(size_t)row * H + col];
        float hn = (1.0f - vz) * vn + vz * ho;
        hf_new[(size_t)row * H + col] = hn;
        hbf_new[(size_t)row * H + col] = f2bf_rne(hn);
    }
}

// out[b][t][o] = sum_h y1[t][b][h] * W[o][h] + bias[o]   (pure fp32)
__global__ __launch_bounds__(256) void k_proj(const float* __restrict__ y1,
                                              const float* __restrict__ W,
                                              const float* __restrict__ bias,
                                              float* __restrict__ out) {
    int idx = blockIdx.x * 256 + threadIdx.x;
    if (idx >= TDEC * BB * 32) return;
    int o = idx & 31;
    int rt = idx >> 5;        // t*BB + b
    int t = rt >> 7;
    int b = rt & (BB - 1);
    const float4* yr = (const float4*)(y1 + (size_t)rt * H);
    const float4* wr = (const float4*)(W + (size_t)o * H);
    float s = 0.f;
    #pragma unroll 4
    for (int k = 0; k < H / 4; ++k) {
        float4 a = yr[k], w = wr[k];
        s += a.x * w.x + a.y * w.y + a.z * w.z + a.w * w.w;
    }
    out[(size_t)b * TDEC * 32 + (size_t)t * 32 + o] = s + bias[o];
}

extern "C" void kernel_launch(void* const* d_in, const int* in_sizes, int n_in,
                              void* d_out, int out_size, void* d_ws, size_t ws_size,
                              hipStream_t stream) {
    const float* x_enc = (const float*)d_in[0];
    const float* x_dec = (const float*)d_in[2];
    const float* eWih0 = (const float*)d_in[4];
    const float* eWhh0 = (const float*)d_in[5];
    const float* ebih0 = (const float*)d_in[6];
    const float* ebhh0 = (const float*)d_in[7];
    const float* eWih1 = (const float*)d_in[8];
    const float* eWhh1 = (const float*)d_in[9];
    const float* ebih1 = (const float*)d_in[10];
    const float* ebhh1 = (const float*)d_in[11];
    const float* dWih0 = (const float*)d_in[12];
    const float* dWhh0 = (const float*)d_in[13];
    const float* dbih0 = (const float*)d_in[14];
    const float* dbhh0 = (const float*)d_in[15];
    const float* dWih1 = (const float*)d_in[16];
    const float* dWhh1 = (const float*)d_in[17];
    const float* dbih1 = (const float*)d_in[18];
    const float* dbhh1 = (const float*)d_in[19];
    const float* outW  = (const float*)d_in[20];
    const float* outb  = (const float*)d_in[21];
    float* out = (float*)d_out;

    char* ws = (char*)d_ws;
    size_t off = 0;
    auto alloc = [&](size_t bytes) -> void* {
        void* p = ws + off;
        off += (bytes + 255) & ~(size_t)255;
        return p;
    };
    const size_t HS = (size_t)BB * H;                  // elems per hidden state
    short* wih0e  = (short*)alloc((size_t)G * 32 * 2);
    short* whh0e  = (short*)alloc((size_t)G * H * 2);
    short* wih1e  = (short*)alloc((size_t)G * H * 2);
    short* whh1e  = (short*)alloc((size_t)G * H * 2);
    short* wih0d  = (short*)alloc((size_t)G * 32 * 2);
    short* whh0d  = (short*)alloc((size_t)G * H * 2);
    short* wih1d  = (short*)alloc((size_t)G * H * 2);
    short* whh1d  = (short*)alloc((size_t)G * H * 2);
    short* xencbf = (short*)alloc((size_t)BB * TENC * 32 * 2);
    short* decinbf= (short*)alloc((size_t)BB * TDEC * 32 * 2);
    short* y0enc  = (short*)alloc((size_t)(TENC + 1) * HS * 2); // slot 0 = zeros
    short* y0dec  = (short*)alloc((size_t)TDEC * HS * 2);
    float* pp0    = (float*)alloc(2 * HS * 4);
    float* pp1    = (float*)alloc(2 * HS * 4);
    short* hbf1   = (short*)alloc(2 * HS * 2);
    float* y1     = (float*)alloc((size_t)TDEC * HS * 4);
    (void)ws_size; (void)in_sizes; (void)n_in; (void)out_size;

    // zero-init initial states
    hipMemsetAsync(y0enc, 0, HS * 2, stream);
    hipMemsetAsync(pp0, 0, HS * 4, stream);
    hipMemsetAsync(pp1, 0, HS * 4, stream);
    hipMemsetAsync(hbf1, 0, HS * 2, stream);

    // weight/input conversions to bf16
    auto cvt = [&](const float* src, short* dst, int n) {
        int blocks = (n + 255) / 256;
        if (blocks > 2048) blocks = 2048;
        k_f2bf<<<dim3(blocks), dim3(256), 0, stream>>>(src, dst, n);
    };
    cvt(eWih0, wih0e, G * 32);
    cvt(eWhh0, whh0e, G * H);
    cvt(eWih1, wih1e, G * H);
    cvt(eWhh1, whh1e, G * H);
    cvt(dWih0, wih0d, G * 32);
    cvt(dWhh0, whh0d, G * H);
    cvt(dWih1, wih1d, G * H);
    cvt(dWhh1, whh1d, G * H);
    cvt(x_enc, xencbf, BB * TENC * 32);
    k_build_decin<<<dim3((BB * TDEC * 32 + 255) / 256), dim3(256), 0, stream>>>(
        x_enc, x_dec, decinbf);

    const dim3 sg(8, 64), sb(64);

    // encoder layer 0: h'_bf -> y0enc[t+1]
    for (int t = 0; t < TENC; ++t) {
        const short* hbo = y0enc + (size_t)t * HS;
        short* hbn = y0enc + (size_t)(t + 1) * HS;
        const float* hfo = pp0 + (size_t)(t & 1) * HS;
        float* hfn = pp0 + (size_t)((t + 1) & 1) * HS;
        k_step_small<<<sg, sb, 0, stream>>>(xencbf, TENC * 32, t * 32,
            wih0e, whh0e, ebih0, ebhh0, hbo, hfo, hbn, hfn);
    }
    // encoder layer 1
    for (int t = 0; t < TENC; ++t) {
        const short* yin = y0enc + (size_t)(t + 1) * HS;
        const short* hbo = hbf1 + (size_t)(t & 1) * HS;
        short* hbn = hbf1 + (size_t)((t + 1) & 1) * HS;
        const float* hfo = pp1 + (size_t)(t & 1) * HS;
        float* hfn = pp1 + (size_t)((t + 1) & 1) * HS;
        k_step_big<<<sg, sb, 0, stream>>>(yin, wih1e, whh1e, ebih1, ebhh1,
            hbo, hfo, hbn, hfn);
    }
    // decoder layer 0 (enc ended with state in pp0[0] / y0enc[TENC])
    for (int t = 0; t < TDEC; ++t) {
        const short* hbo = (t == 0) ? (y0enc + (size_t)TENC * HS)
                                    : (y0dec + (size_t)(t - 1) * HS);
        short* hbn = y0dec + (size_t)t * HS;
        const float* hfo = pp0 + (size_t)(t & 1) * HS;
        float* hfn = pp0 + (size_t)((t + 1) & 1) * HS;
        k_step_small<<<sg, sb, 0, stream>>>(decinbf, TDEC * 32, t * 32,
            wih0d, whh0d, dbih0, dbhh0, hbo, hfo, hbn, hfn);
    }
    // decoder layer 1 (enc ended with state in pp1[0] / hbf1[0]); fp32 h -> y1[t]
    for (int t = 0; t < TDEC; ++t) {
        const short* yin = y0dec + (size_t)t * HS;
        const short* hbo = hbf1 + (size_t)(t & 1) * HS;
        short* hbn = hbf1 + (size_t)((t + 1) & 1) * HS;
        const float* hfo = (t == 0) ? pp1 : (y1 + (size_t)(t - 1) * HS);
        float* hfn = y1 + (size_t)t * HS;
        k_step_big<<<sg, sb, 0, stream>>>(yin, wih1d, whh1d, dbih1, dbhh1,
            hbo, hfo, hbn, hfn);
    }
    // output projection (fp32)
    k_proj<<<dim3((TDEC * BB * 32 + 255) / 256), dim3(256), 0, stream>>>(
        y1, outW, outb, out);
}

// Round 2
// 7593.822 us; speedup vs baseline: 1.3713x; 1.3713x over previous
//
#include <hip/hip_runtime.h>
#include <hip/hip_bf16.h>

// Seq2seq GRU (2-layer enc T=192, 2-layer dec T=96), B=128, H=1024.
// Round 1: (a) XCD-friendly grid mapping (i-tile on blockIdx.x so weight
// slices stay L2-resident per XCD), (b) diagonal layer pipelining: one fused
// kernel per step computes L0[s] and L1[s-1] concurrently (290 launches vs
// 576). bf16 MFMA (fp32 accum), fp32 master hidden state, fp32 projection.

#define H 1024
#define G 3072   /* 3*H */
#define BB 128
#define TENC 192
#define TDEC 96

typedef __attribute__((ext_vector_type(4))) float f32x4;
typedef __attribute__((ext_vector_type(8))) short bf16x8;

__device__ __forceinline__ float sigmoidf_(float x) {
    return 1.0f / (1.0f + __expf(-x));
}

__device__ __forceinline__ short f2bf_rne(float f) {
    union { float f; unsigned u; } v; v.f = f;
    unsigned r = v.u + 0x7fffu + ((v.u >> 16) & 1u);
    return (short)(r >> 16);
}

__global__ __launch_bounds__(256) void k_f2bf(const float* __restrict__ in,
                                              short* __restrict__ out, int n) {
    for (int i = blockIdx.x * 256 + threadIdx.x; i < n; i += gridDim.x * 256)
        out[i] = f2bf_rne(in[i]);
}

// dec_in[b][t][c]: t==0 -> x_enc[b][191][c], else x_dec[b][t-1][c]
__global__ __launch_bounds__(256) void k_build_decin(const float* __restrict__ x_enc,
                                                     const float* __restrict__ x_dec,
                                                     short* __restrict__ out) {
    int i = blockIdx.x * 256 + threadIdx.x;
    if (i >= BB * TDEC * 32) return;
    int c = i & 31;
    int t = (i >> 5) % TDEC;
    int b = i / (TDEC * 32);
    float v = (t == 0) ? x_enc[(size_t)b * TENC * 32 + 191 * 32 + c]
                       : x_dec[(size_t)b * TDEC * 32 + (t - 1) * 32 + c];
    out[i] = f2bf_rne(v);
}

// ---- GRU cell bodies (one wave = 16(b) x 16(i) tile, all 3 gates) ----
// blockIdx.x = i-tile (0..63)  [fastest-varying -> XCD = i%8, stable across
// launches so each XCD's weight slice stays L2-resident]
// blockIdx.y = b-tile (0..7)

__device__ __forceinline__ void cell_small(
    const short* __restrict__ xbf, int xstride, int xoff,
    const short* __restrict__ wih,   // [G][32]
    const short* __restrict__ whh,   // [G][H]
    const float* __restrict__ bih, const float* __restrict__ bhh,
    const short* __restrict__ hbf_old, const float* __restrict__ hf_old,
    short* __restrict__ hbf_new, float* __restrict__ hf_new)
{
    const int lane = threadIdx.x & 63;
    const int lr = lane & 15;
    const int kg = lane >> 4;
    const int i0 = blockIdx.x * 16;
    const int b0 = blockIdx.y * 16;

    f32x4 accR = {0.f, 0.f, 0.f, 0.f};
    f32x4 accZ = accR, accGN = accR, accHN = accR;

    const short* ar = hbf_old + (size_t)(b0 + lr) * H + kg * 8;
    const short* wr = whh + (size_t)(i0 + lr) * H + kg * 8;
    const short* wz = wr + (size_t)H * H;
    const short* wn = wr + (size_t)(2 * H) * H;

    #pragma unroll 4
    for (int kk = 0; kk < H; kk += 32) {
        bf16x8 a  = *(const bf16x8*)(ar + kk);
        bf16x8 br = *(const bf16x8*)(wr + kk);
        bf16x8 bz = *(const bf16x8*)(wz + kk);
        bf16x8 bn = *(const bf16x8*)(wn + kk);
        accR  = __builtin_amdgcn_mfma_f32_16x16x32_bf16(a, br, accR, 0, 0, 0);
        accZ  = __builtin_amdgcn_mfma_f32_16x16x32_bf16(a, bz, accZ, 0, 0, 0);
        accHN = __builtin_amdgcn_mfma_f32_16x16x32_bf16(a, bn, accHN, 0, 0, 0);
    }
    {   // gi: K=32 input matmul, single MFMA chunk per gate
        bf16x8 a  = *(const bf16x8*)(xbf + (size_t)(b0 + lr) * xstride + xoff + kg * 8);
        bf16x8 br = *(const bf16x8*)(wih + (size_t)(i0 + lr) * 32 + kg * 8);
        bf16x8 bz = *(const bf16x8*)(wih + (size_t)(H + i0 + lr) * 32 + kg * 8);
        bf16x8 bn = *(const bf16x8*)(wih + (size_t)(2 * H + i0 + lr) * 32 + kg * 8);
        accR  = __builtin_amdgcn_mfma_f32_16x16x32_bf16(a, br, accR, 0, 0, 0);
        accZ  = __builtin_amdgcn_mfma_f32_16x16x32_bf16(a, bz, accZ, 0, 0, 0);
        accGN = __builtin_amdgcn_mfma_f32_16x16x32_bf16(a, bn, accGN, 0, 0, 0);
    }
    const int col = i0 + lr;
    const float bR  = bih[col] + bhh[col];
    const float bZ  = bih[H + col] + bhh[H + col];
    const float bGN = bih[2 * H + col];
    const float bHN = bhh[2 * H + col];
    #pragma unroll
    for (int r = 0; r < 4; ++r) {
        int row = b0 + kg * 4 + r;            // C/D: row = 4*(lane>>4)+reg
        float vr = sigmoidf_(accR[r] + bR);
        float vz = sigmoidf_(accZ[r] + bZ);
        float vn = tanhf(accGN[r] + bGN + vr * (accHN[r] + bHN));
        float ho = hf_old[(size_t)row * H + col];
        float hn = (1.0f - vz) * vn + vz * ho;
        hf_new[(size_t)row * H + col] = hn;
        hbf_new[(size_t)row * H + col] = f2bf_rne(hn);
    }
}

__device__ __forceinline__ void cell_big(
    const short* __restrict__ ybf,   // [BB][H] lower-layer output at t
    const short* __restrict__ wih,   // [G][H]
    const short* __restrict__ whh,   // [G][H]
    const float* __restrict__ bih, const float* __restrict__ bhh,
    const short* __restrict__ hbf_old, const float* __restrict__ hf_old,
    short* __restrict__ hbf_new, float* __restrict__ hf_new)
{
    const int lane = threadIdx.x & 63;
    const int lr = lane & 15;
    const int kg = lane >> 4;
    const int i0 = blockIdx.x * 16;
    const int b0 = blockIdx.y * 16;

    f32x4 accR = {0.f, 0.f, 0.f, 0.f};
    f32x4 accZ = accR, accGN = accR, accHN = accR;

    const short* ay = ybf + (size_t)(b0 + lr) * H + kg * 8;
    const short* ah = hbf_old + (size_t)(b0 + lr) * H + kg * 8;
    const short* wir = wih + (size_t)(i0 + lr) * H + kg * 8;
    const short* wiz = wir + (size_t)H * H;
    const short* win = wir + (size_t)(2 * H) * H;
    const short* whr = whh + (size_t)(i0 + lr) * H + kg * 8;
    const short* whz = whr + (size_t)H * H;
    const short* whn = whr + (size_t)(2 * H) * H;

    #pragma unroll 2
    for (int kk = 0; kk < H; kk += 32) {
        bf16x8 vy  = *(const bf16x8*)(ay + kk);
        bf16x8 vh  = *(const bf16x8*)(ah + kk);
        bf16x8 vir = *(const bf16x8*)(wir + kk);
        bf16x8 viz = *(const bf16x8*)(wiz + kk);
        bf16x8 vin = *(const bf16x8*)(win + kk);
        bf16x8 vhr = *(const bf16x8*)(whr + kk);
        bf16x8 vhz = *(const bf16x8*)(whz + kk);
        bf16x8 vhn = *(const bf16x8*)(whn + kk);
        accR  = __builtin_amdgcn_mfma_f32_16x16x32_bf16(vy, vir, accR, 0, 0, 0);
        accR  = __builtin_amdgcn_mfma_f32_16x16x32_bf16(vh, vhr, accR, 0, 0, 0);
        accZ  = __builtin_amdgcn_mfma_f32_16x16x32_bf16(vy, viz, accZ, 0, 0, 0);
        accZ  = __builtin_amdgcn_mfma_f32_16x16x32_bf16(vh, vhz, accZ, 0, 0, 0);
        accGN = __builtin_amdgcn_mfma_f32_16x16x32_bf16(vy, vin, accGN, 0, 0, 0);
        accHN = __builtin_amdgcn_mfma_f32_16x16x32_bf16(vh, vhn, accHN, 0, 0, 0);
    }
    const int col = i0 + lr;
    const float bR  = bih[col] + bhh[col];
    const float bZ  = bih[H + col] + bhh[H + col];
    const float bGN = bih[2 * H + col];
    const float bHN = bhh[2 * H + col];
    #pragma unroll
    for (int r = 0; r < 4; ++r) {
        int row = b0 + kg * 4 + r;
        float vr = sigmoidf_(accR[r] + bR);
        float vz = sigmoidf_(accZ[r] + bZ);
        float vn = tanhf(accGN[r] + bGN + vr * (accHN[r] + bHN));
        float ho = hf_old[(size_t)row * H + col];
        float hn = (1.0f - vz) * vn + vz * ho;
        hf_new[(size_t)row * H + col] = hn;
        hbf_new[(size_t)row * H + col] = f2bf_rne(hn);
    }
}

// One diagonal step: z=0 -> L0 cell at time s; z=1 -> L1 cell at time s-1.
__global__ __launch_bounds__(64) void k_step_dual(
    const short* __restrict__ x, int xstride, int xoff,
    const short* __restrict__ wih0, const short* __restrict__ whh0,
    const float* __restrict__ bih0, const float* __restrict__ bhh0,
    const short* __restrict__ h0b_old, const float* __restrict__ h0f_old,
    short* __restrict__ h0b_new, float* __restrict__ h0f_new,
    const short* __restrict__ wih1, const short* __restrict__ whh1,
    const float* __restrict__ bih1, const float* __restrict__ bhh1,
    const short* __restrict__ y0in, const short* __restrict__ h1b_old,
    const float* __restrict__ h1f_old,
    short* __restrict__ h1b_new, float* __restrict__ h1f_new,
    int act0, int act1)
{
    if (blockIdx.z == 0) {
        if (!act0) return;
        cell_small(x, xstride, xoff, wih0, whh0, bih0, bhh0,
                   h0b_old, h0f_old, h0b_new, h0f_new);
    } else {
        if (!act1) return;
        cell_big(y0in, wih1, whh1, bih1, bhh1,
                 h1b_old, h1f_old, h1b_new, h1f_new);
    }
}

// out[b][t][o] = sum_h y1[t][b][h] * W[o][h] + bias[o]   (pure fp32)
__global__ __launch_bounds__(256) void k_proj(const float* __restrict__ y1,
                                              const float* __restrict__ W,
                                              const float* __restrict__ bias,
                                              float* __restrict__ out) {
    int idx = blockIdx.x * 256 + threadIdx.x;
    if (idx >= TDEC * BB * 32) return;
    int o = idx & 31;
    int rt = idx >> 5;        // t*BB + b
    int t = rt >> 7;
    int b = rt & (BB - 1);
    const float4* yr = (const float4*)(y1 + (size_t)rt * H);
    const float4* wr = (const float4*)(W + (size_t)o * H);
    float s = 0.f;
    #pragma unroll 4
    for (int k = 0; k < H / 4; ++k) {
        float4 a = yr[k], w = wr[k];
        s += a.x * w.x + a.y * w.y + a.z * w.z + a.w * w.w;
    }
    out[(size_t)b * TDEC * 32 + (size_t)t * 32 + o] = s + bias[o];
}

extern "C" void kernel_launch(void* const* d_in, const int* in_sizes, int n_in,
                              void* d_out, int out_size, void* d_ws, size_t ws_size,
                              hipStream_t stream) {
    const float* x_enc = (const float*)d_in[0];
    const float* x_dec = (const float*)d_in[2];
    const float* eWih0 = (const float*)d_in[4];
    const float* eWhh0 = (const float*)d_in[5];
    const float* ebih0 = (const float*)d_in[6];
    const float* ebhh0 = (const float*)d_in[7];
    const float* eWih1 = (const float*)d_in[8];
    const float* eWhh1 = (const float*)d_in[9];
    const float* ebih1 = (const float*)d_in[10];
    const float* ebhh1 = (const float*)d_in[11];
    const float* dWih0 = (const float*)d_in[12];
    const float* dWhh0 = (const float*)d_in[13];
    const float* dbih0 = (const float*)d_in[14];
    const float* dbhh0 = (const float*)d_in[15];
    const float* dWih1 = (const float*)d_in[16];
    const float* dWhh1 = (const float*)d_in[17];
    const float* dbih1 = (const float*)d_in[18];
    const float* dbhh1 = (const float*)d_in[19];
    const float* outW  = (const float*)d_in[20];
    const float* outb  = (const float*)d_in[21];
    float* out = (float*)d_out;

    char* ws = (char*)d_ws;
    size_t off = 0;
    auto alloc = [&](size_t bytes) -> void* {
        void* p = ws + off;
        off += (bytes + 255) & ~(size_t)255;
        return p;
    };
    const size_t HS = (size_t)BB * H;                  // elems per hidden state
    short* wih0e  = (short*)alloc((size_t)G * 32 * 2);
    short* whh0e  = (short*)alloc((size_t)G * H * 2);
    short* wih1e  = (short*)alloc((size_t)G * H * 2);
    short* whh1e  = (short*)alloc((size_t)G * H * 2);
    short* wih0d  = (short*)alloc((size_t)G * 32 * 2);
    short* whh0d  = (short*)alloc((size_t)G * H * 2);
    short* wih1d  = (short*)alloc((size_t)G * H * 2);
    short* whh1d  = (short*)alloc((size_t)G * H * 2);
    short* xencbf = (short*)alloc((size_t)BB * TENC * 32 * 2);
    short* decinbf= (short*)alloc((size_t)BB * TDEC * 32 * 2);
    short* y0r    = (short*)alloc(2 * HS * 2);   // L0 state ring (bf16)
    float* pp0    = (float*)alloc(2 * HS * 4);   // L0 state ring (f32)
    short* hbf1   = (short*)alloc(2 * HS * 2);   // L1 state ring (bf16)
    float* pp1    = (float*)alloc(2 * HS * 4);   // enc L1 state ring (f32)
    float* y1     = (float*)alloc((size_t)TDEC * HS * 4);  // dec L1 f32 history
    (void)ws_size; (void)in_sizes; (void)n_in; (void)out_size;

    // zero-init initial states (slot 0 of each ring)
    hipMemsetAsync(y0r, 0, HS * 2, stream);
    hipMemsetAsync(pp0, 0, HS * 4, stream);
    hipMemsetAsync(hbf1, 0, HS * 2, stream);
    hipMemsetAsync(pp1, 0, HS * 4, stream);

    // weight/input conversions to bf16
    auto cvt = [&](const float* src, short* dst, int n) {
        int blocks = (n + 255) / 256;
        if (blocks > 2048) blocks = 2048;
        k_f2bf<<<dim3(blocks), dim3(256), 0, stream>>>(src, dst, n);
    };
    cvt(eWih0, wih0e, G * 32);
    cvt(eWhh0, whh0e, G * H);
    cvt(eWih1, wih1e, G * H);
    cvt(eWhh1, whh1e, G * H);
    cvt(dWih0, wih0d, G * 32);
    cvt(dWhh0, whh0d, G * H);
    cvt(dWih1, wih1d, G * H);
    cvt(dWhh1, whh1d, G * H);
    cvt(x_enc, xencbf, BB * TENC * 32);
    k_build_decin<<<dim3((BB * TDEC * 32 + 255) / 256), dim3(256), 0, stream>>>(
        x_enc, x_dec, decinbf);

    const dim3 dg(64, 8, 2), db(64);

    // ---- encoder: diagonal steps s = 0..TENC ----
    for (int s = 0; s <= TENC; ++s) {
        int act0 = (s < TENC), act1 = (s >= 1);
        const short* h0b_old = y0r + (size_t)(s & 1) * HS;
        short*       h0b_new = y0r + (size_t)((s + 1) & 1) * HS;
        const float* h0f_old = pp0 + (size_t)(s & 1) * HS;
        float*       h0f_new = pp0 + (size_t)((s + 1) & 1) * HS;
        const short* y0in    = y0r + (size_t)(s & 1) * HS;      // h0 after t=s-1
        const short* h1b_old = hbf1 + (size_t)((s - 1) & 1) * HS;
        short*       h1b_new = hbf1 + (size_t)(s & 1) * HS;
        const float* h1f_old = pp1 + (size_t)((s - 1) & 1) * HS;
        float*       h1f_new = pp1 + (size_t)(s & 1) * HS;
        k_step_dual<<<dg, db, 0, stream>>>(
            xencbf, TENC * 32, s * 32,
            wih0e, whh0e, ebih0, ebhh0, h0b_old, h0f_old, h0b_new, h0f_new,
            wih1e, whh1e, ebih1, ebhh1, y0in, h1b_old, h1f_old, h1b_new, h1f_new,
            act0, act1);
    }
    // ---- decoder: diagonal steps s = 0..TDEC ----
    // L0 state continues in y0r/pp0 (enc left state in slot 0 = TENC&1).
    // L1 bf state continues in hbf1 (slot 0); f32 master: pp1[0] -> y1[t].
    for (int s = 0; s <= TDEC; ++s) {
        int act0 = (s < TDEC), act1 = (s >= 1);
        const short* h0b_old = y0r + (size_t)(s & 1) * HS;
        short*       h0b_new = y0r + (size_t)((s + 1) & 1) * HS;
        const float* h0f_old = pp0 + (size_t)(s & 1) * HS;
        float*       h0f_new = pp0 + (size_t)((s + 1) & 1) * HS;
        const short* y0in    = y0r + (size_t)(s & 1) * HS;      // h0 after t=s-1
        const short* h1b_old = hbf1 + (size_t)((s - 1) & 1) * HS;
        short*       h1b_new = hbf1 + (size_t)(s & 1) * HS;
        const float* h1f_old = (s == 1) ? pp1 : (y1 + (size_t)(s - 2) * HS);
        float*       h1f_new = y1 + (size_t)(s - 1) * HS;       // unused if act1=0
        if (s == 0) h1f_new = pp1 + HS;                         // dummy, never read
        k_step_dual<<<dg, db, 0, stream>>>(
            decinbf, TDEC * 32, s * 32,
            wih0d, whh0d, dbih0, dbhh0, h0b_old, h0f_old, h0b_new, h0f_new,
            wih1d, whh1d, dbih1, dbhh1, y0in, h1b_old, h1f_old, h1b_new, h1f_new,
            act0, act1);
    }
    // output projection (fp32)
    k_proj<<<dim3((TDEC * BB * 32 + 255) / 256), dim3(256), 0, stream>>>(
        y1, outW, outb, out);
}